// Round 5
// baseline (1187.612 us; speedup 1.0000x reference)
//
#include <hip/hip_runtime.h>
#include <hip/hip_fp16.h>

#define TSEQ  2048
#define BATCH 64
#define DIN   128
#define DH    256
#define WSTR  384   // W row stride = dimIn + dimH
#define NCH   (TSEQ / 16)

typedef __fp16 h2    __attribute__((ext_vector_type(2)));
typedef __fp16 f16x8 __attribute__((ext_vector_type(8)));
typedef float  f32x4 __attribute__((ext_vector_type(4)));

static __device__ __forceinline__ h2 bc_h2(unsigned int u) {
    return __builtin_bit_cast(h2, u);
}

// Pure-VALU cross-lane exchanges (no DS pipe):
// quad_perm xor1: [1,0,3,2] = 0xB1 ; xor2: [2,3,0,1] = 0x4E
// xor8: row_ror:8 (0x128) — within a 16-lane row, (i+8)%16 == i^8
#define DPP_XOR1(v) __builtin_bit_cast(float, \
    __builtin_amdgcn_mov_dpp(__builtin_bit_cast(int, (v)), 0xB1, 0xF, 0xF, true))
#define DPP_XOR2(v) __builtin_bit_cast(float, \
    __builtin_amdgcn_mov_dpp(__builtin_bit_cast(int, (v)), 0x4E, 0xF, 0xF, true))
#define DPP_XOR8(v) __builtin_bit_cast(float, \
    __builtin_amdgcn_mov_dpp(__builtin_bit_cast(int, (v)), 0x128, 0xF, 0xF, true))

// pair-sum across lane^32 via ds_bpermute (the standard __shfl_xor(32)
// lowering — hardware-verified primitive). v5's v_permlane32_swap with
// identical tied inputs could legally coalesce to one register (in-place
// half-swap => dot = 2*U[l^32]) — suspected cause of the v5 absmax failure.
static __device__ __forceinline__ float pair_sum32(float u, int lane) {
    const int addr = (lane ^ 32) << 2;   // byte index of partner lane
    float v = __builtin_bit_cast(float,
        __builtin_amdgcn_ds_bpermute(addr, __builtin_bit_cast(int, u)));
    return u + v;
}

// ---------------- Fused kernel: on-the-fly xw (MFMA) + sequential scan -------
// One block per batch (64 blocks on 256 CUs -> each block gets its own CU),
// 512 threads = 8 waves = 2 waves/SIMD: one wave's ds_read/tanh latency hides
// under the other wave's v_dot2 issue.
//
// Scan decomposition: output o(t) = tid with bit5 dropped; k split 16 ways,
// sigma(t) from tid bits {0,1,3,5}. Thread t computes partials for outputs
// o^rho, rho in span{1,2,8} (8 outputs x 16 k = 64 fdot2). Reduction:
// DPP xor1/xor2/xor8 (tid bits 0,1,3) + ds_bpermute pair-sum (tid bit5).
//
// xw: computed per-chunk (16 steps) by 8 MFMAs/wave into a ping-pong LDS
// buffer one chunk ahead (matrix pipe, hidden under the VALU dots). Replaces
// the separate GEMM kernel AND its 128MB xw write + 128MB xw read.
__global__ __launch_bounds__(512) void rnn_fused(const float* __restrict__ x,
                                                 const float* __restrict__ W,
                                                 const float* __restrict__ bias,
                                                 const float* __restrict__ h0,
                                                 float* __restrict__ out) {
    __shared__ __align__(16) __fp16 hseg[2][16][24];   // 16 segs of 16, stride 48B
    __shared__ __align__(16) float  xwb[2][16][DH];    // ping-pong xw chunk (32 KB)

    const int tid  = threadIdx.x;
    const int b    = blockIdx.x;
    const int lane = tid & 63;
    const int wv   = tid >> 6;
    const int nlo  = lane & 15;
    const int quad = lane >> 4;

    const int o   = (tid & 31) | ((tid >> 1) & 224);                    // drop bit5
    const int sig = (tid & 3) | ((tid & 8) >> 1) | ((tid & 32) >> 2);   // k-seg [0,16)

    // ---- Wh fragments: 8 relative rows x 16 k -> 64 VGPRs ----
    h2 w[8][8];
#pragma unroll
    for (int r = 0; r < 8; ++r) {
        const int rho = (r & 3) | ((r & 4) << 1);     // {0,1,2,3,8,9,10,11}
        const float* wr = W + (size_t)(o ^ rho) * WSTR + DIN + 16 * sig;
#pragma unroll
        for (int j = 0; j < 4; ++j) {
            float4 f = *(const float4*)(wr + 4 * j);
            w[r][2 * j]     = h2{(__fp16)f.x, (__fp16)f.y};
            w[r][2 * j + 1] = h2{(__fp16)f.z, (__fp16)f.w};
        }
    }
    // pin w into VGPRs (v_dot2 can't read AGPRs; demotion = accvgpr_read/use)
#pragma unroll
    for (int r = 0; r < 8; ++r)
#pragma unroll
        for (int i = 0; i < 8; ++i)
            asm volatile("" : "+v"(w[r][i]));

    // ---- Wx B-fragments (resident) + bias: wave wv owns xw cols [32wv,32wv+32) ----
    f16x8 bfr[2][4];
#pragma unroll
    for (int n0 = 0; n0 < 2; ++n0) {
        const float* wr = W + (size_t)(32 * wv + 16 * n0 + nlo) * WSTR;
#pragma unroll
        for (int kk = 0; kk < 4; ++kk) {
            float4 f0 = *(const float4*)(wr + kk * 32 + quad * 8);
            float4 f1 = *(const float4*)(wr + kk * 32 + quad * 8 + 4);
            f16x8 v;
            v[0]=(__fp16)f0.x; v[1]=(__fp16)f0.y; v[2]=(__fp16)f0.z; v[3]=(__fp16)f0.w;
            v[4]=(__fp16)f1.x; v[5]=(__fp16)f1.y; v[6]=(__fp16)f1.z; v[7]=(__fp16)f1.w;
            bfr[n0][kk] = v;
        }
    }
    const float bias0 = bias[32 * wv + nlo];
    const float bias1 = bias[32 * wv + 16 + nlo];

    // ---- x chunk in registers (A-frag source rows = nlo) ----
    const float* xb = x + (size_t)b * TSEQ * DIN;
    float4 xr[8];

#define LOAD_X(c)                                                            \
    {                                                                        \
        const float* xp = xb + (size_t)(16 * (c) + nlo) * DIN;               \
        _Pragma("unroll")                                                    \
        for (int kk = 0; kk < 4; ++kk) {                                     \
            xr[2 * kk]     = *(const float4*)(xp + kk * 32 + quad * 8);      \
            xr[2 * kk + 1] = *(const float4*)(xp + kk * 32 + quad * 8 + 4);  \
        }                                                                    \
    }

#define MAKE_XW(buf)                                                         \
    {                                                                        \
        f32x4 a0 = (f32x4)0.0f, a1 = (f32x4)0.0f;                            \
        _Pragma("unroll")                                                    \
        for (int kk = 0; kk < 4; ++kk) {                                     \
            float4 f0 = xr[2 * kk], f1 = xr[2 * kk + 1];                     \
            f16x8 a;                                                         \
            a[0]=(__fp16)f0.x; a[1]=(__fp16)f0.y; a[2]=(__fp16)f0.z;         \
            a[3]=(__fp16)f0.w; a[4]=(__fp16)f1.x; a[5]=(__fp16)f1.y;         \
            a[6]=(__fp16)f1.z; a[7]=(__fp16)f1.w;                            \
            a0 = __builtin_amdgcn_mfma_f32_16x16x32_f16(a, bfr[0][kk], a0, 0, 0, 0); \
            a1 = __builtin_amdgcn_mfma_f32_16x16x32_f16(a, bfr[1][kk], a1, 0, 0, 0); \
        }                                                                    \
        _Pragma("unroll")                                                    \
        for (int r = 0; r < 4; ++r) {                                        \
            xwb[buf][quad * 4 + r][32 * wv + nlo]      = a0[r] + bias0;      \
            xwb[buf][quad * 4 + r][32 * wv + 16 + nlo] = a1[r] + bias1;      \
        }                                                                    \
    }

    if (tid < DH) hseg[0][tid >> 4][tid & 15] = (__fp16)h0[(size_t)b * DH + tid];

    LOAD_X(0);
    MAKE_XW(0);          // compiler inserts the vmcnt wait for xr
    LOAD_X(1);
    __syncthreads();     // one full drain in prologue only

    float* orow = out + (size_t)b * TSEQ * DH + o;

#pragma unroll 1
    for (int c = 0; c < NCH; ++c) {
        if (c + 1 < NCH) {
            MAKE_XW((c + 1) & 1);                    // xw for next chunk (other buffer)
            LOAD_X(c + 2 < NCH ? c + 2 : 0);         // prefetch x two chunks ahead
        }
        const float* xwr = &xwb[c & 1][0][0];
        float* oc = orow + (size_t)(16 * c) * DH;

#pragma unroll
        for (int s = 0; s < 16; ++s) {
            const float xw_s = xwr[s * DH + o];      // issued early, used at tanh
            const int p = s & 1;                     // ping-pong parity (compile-time)
            const uint4* hp = (const uint4*)&hseg[p][sig][0];
            uint4 v0 = hp[0], v1 = hp[1];
            h2 ha = bc_h2(v0.x), hb = bc_h2(v0.y), hc = bc_h2(v0.z), hd = bc_h2(v0.w);
            h2 he = bc_h2(v1.x), hf = bc_h2(v1.y), hg = bc_h2(v1.z), hh = bc_h2(v1.w);

            float P[8];
#pragma unroll
            for (int r = 0; r < 8; ++r) {
                P[r] = __builtin_amdgcn_fdot2(w[r][0], ha, 0.0f, false);
                P[r] = __builtin_amdgcn_fdot2(w[r][1], hb, P[r], false);
                P[r] = __builtin_amdgcn_fdot2(w[r][2], hc, P[r], false);
                P[r] = __builtin_amdgcn_fdot2(w[r][3], hd, P[r], false);
                P[r] = __builtin_amdgcn_fdot2(w[r][4], he, P[r], false);
                P[r] = __builtin_amdgcn_fdot2(w[r][5], hf, P[r], false);
                P[r] = __builtin_amdgcn_fdot2(w[r][6], hg, P[r], false);
                P[r] = __builtin_amdgcn_fdot2(w[r][7], hh, P[r], false);
            }

            // butterfly over tid bits {0,1,3} (DPP) then bit5 (ds_bpermute).
            float S0 = P[0] + DPP_XOR1(P[1]);
            float S1 = P[2] + DPP_XOR1(P[3]);
            float S2 = P[4] + DPP_XOR1(P[5]);
            float S3 = P[6] + DPP_XOR1(P[7]);
            float T0 = S0 + DPP_XOR2(S1);
            float T1 = S2 + DPP_XOR2(S3);
            float U  = T0 + DPP_XOR8(T1);
            float dot = pair_sum32(U, lane);

            if (!(tid & 32)) {                       // one owner per output
                float pre = xw_s + dot;
                // tanh(x) = 1 - 2/(e^(2x)+1)
                float e  = __expf(2.0f * pre);
                float hn = 1.0f - 2.0f * __builtin_amdgcn_rcpf(e + 1.0f);
                hseg[p ^ 1][o >> 4][o & 15] = (__fp16)hn;
                oc[(size_t)s * DH] = hn;             // fire-and-forget
            }
            // barrier WITHOUT vmcnt drain: only LDS must be visible.
            asm volatile("s_waitcnt lgkmcnt(0)\n\ts_barrier" ::: "memory");
        }
    }
#undef LOAD_X
#undef MAKE_XW
}

extern "C" void kernel_launch(void* const* d_in, const int* in_sizes, int n_in,
                              void* d_out, int out_size, void* d_ws, size_t ws_size,
                              hipStream_t stream) {
    const float* x    = (const float*)d_in[0];
    const float* h0   = (const float*)d_in[1];
    const float* W    = (const float*)d_in[2];
    const float* bias = (const float*)d_in[3];
    float* out = (float*)d_out;

    rnn_fused<<<BATCH, 512, 0, stream>>>(x, W, bias, h0, out);
}

// Round 6
// 1187.605 us; speedup vs baseline: 1.0000x; 1.0000x over previous
//
#include <hip/hip_runtime.h>
#include <hip/hip_fp16.h>

#define TSEQ  2048
#define BATCH 64
#define DIN   128
#define DH    256
#define WSTR  384   // W row stride = dimIn + dimH
#define NCH   (TSEQ / 16)

typedef __fp16 h2    __attribute__((ext_vector_type(2)));
typedef __fp16 f16x8 __attribute__((ext_vector_type(8)));
typedef float  f32x4 __attribute__((ext_vector_type(4)));

static __device__ __forceinline__ h2 bc_h2(unsigned int u) {
    return __builtin_bit_cast(h2, u);
}

// Pure-VALU cross-lane exchanges (no DS pipe):
// quad_perm xor1: [1,0,3,2] = 0xB1 ; xor2: [2,3,0,1] = 0x4E
// xor8: row_ror:8 (0x128) — within a 16-lane row, (i+8)%16 == i^8
#define DPP_XOR1(v) __builtin_bit_cast(float, \
    __builtin_amdgcn_mov_dpp(__builtin_bit_cast(int, (v)), 0xB1, 0xF, 0xF, true))
#define DPP_XOR2(v) __builtin_bit_cast(float, \
    __builtin_amdgcn_mov_dpp(__builtin_bit_cast(int, (v)), 0x4E, 0xF, 0xF, true))
#define DPP_XOR8(v) __builtin_bit_cast(float, \
    __builtin_amdgcn_mov_dpp(__builtin_bit_cast(int, (v)), 0x128, 0xF, 0xF, true))

// pair-sum across lane^32 via ds_bpermute (hardware-verified in v6).
static __device__ __forceinline__ float pair_sum32(float u, int lane) {
    const int addr = (lane ^ 32) << 2;   // byte index of partner lane
    float v = __builtin_bit_cast(float,
        __builtin_amdgcn_ds_bpermute(addr, __builtin_bit_cast(int, u)));
    return u + v;
}

// ---------------- Fused kernel: on-the-fly xw (MFMA) + sequential scan -------
// One block per batch (64 blocks on 256 CUs -> each block gets its own CU),
// 512 threads = 8 waves = 2 waves/SIMD.
//
// v7 vs v6 (ONE change): __launch_bounds__(512, 2).
// v6's __launch_bounds__(512) without min-waves let the compiler target high
// occupancy -> arch-VGPR cap 88 -> w/bfr/xr (128 dwords of resident state)
// demoted to AGPR homes -> ~64+ v_accvgpr_read per thread per step (VALU
// cyc/step ~3x the dot-issue floor; 1080us vs v3's 794). 2 waves/EU is our
// true residency (1 block/CU) => 256-VGPR budget per wave, state stays in
// VGPRs.
__global__ __launch_bounds__(512, 2) void rnn_fused(const float* __restrict__ x,
                                                    const float* __restrict__ W,
                                                    const float* __restrict__ bias,
                                                    const float* __restrict__ h0,
                                                    float* __restrict__ out) {
    __shared__ __align__(16) __fp16 hseg[2][16][24];   // 16 segs of 16, stride 48B
    __shared__ __align__(16) float  xwb[2][16][DH];    // ping-pong xw chunk (32 KB)

    const int tid  = threadIdx.x;
    const int b    = blockIdx.x;
    const int lane = tid & 63;
    const int wv   = tid >> 6;
    const int nlo  = lane & 15;
    const int quad = lane >> 4;

    const int o   = (tid & 31) | ((tid >> 1) & 224);                    // drop bit5
    const int sig = (tid & 3) | ((tid & 8) >> 1) | ((tid & 32) >> 2);   // k-seg [0,16)

    // ---- Wh fragments: 8 relative rows x 16 k -> 64 VGPRs ----
    h2 w[8][8];
#pragma unroll
    for (int r = 0; r < 8; ++r) {
        const int rho = (r & 3) | ((r & 4) << 1);     // {0,1,2,3,8,9,10,11}
        const float* wr = W + (size_t)(o ^ rho) * WSTR + DIN + 16 * sig;
#pragma unroll
        for (int j = 0; j < 4; ++j) {
            float4 f = *(const float4*)(wr + 4 * j);
            w[r][2 * j]     = h2{(__fp16)f.x, (__fp16)f.y};
            w[r][2 * j + 1] = h2{(__fp16)f.z, (__fp16)f.w};
        }
    }
    // pin w into VGPRs (v_dot2 can't read AGPRs; demotion = accvgpr_read/use)
#pragma unroll
    for (int r = 0; r < 8; ++r)
#pragma unroll
        for (int i = 0; i < 8; ++i)
            asm volatile("" : "+v"(w[r][i]));

    // ---- Wx B-fragments (resident) + bias: wave wv owns xw cols [32wv,32wv+32) ----
    f16x8 bfr[2][4];
#pragma unroll
    for (int n0 = 0; n0 < 2; ++n0) {
        const float* wr = W + (size_t)(32 * wv + 16 * n0 + nlo) * WSTR;
#pragma unroll
        for (int kk = 0; kk < 4; ++kk) {
            float4 f0 = *(const float4*)(wr + kk * 32 + quad * 8);
            float4 f1 = *(const float4*)(wr + kk * 32 + quad * 8 + 4);
            f16x8 v;
            v[0]=(__fp16)f0.x; v[1]=(__fp16)f0.y; v[2]=(__fp16)f0.z; v[3]=(__fp16)f0.w;
            v[4]=(__fp16)f1.x; v[5]=(__fp16)f1.y; v[6]=(__fp16)f1.z; v[7]=(__fp16)f1.w;
            bfr[n0][kk] = v;
        }
    }
    const float bias0 = bias[32 * wv + nlo];
    const float bias1 = bias[32 * wv + 16 + nlo];

    // ---- x chunk in registers (A-frag source rows = nlo) ----
    const float* xb = x + (size_t)b * TSEQ * DIN;
    float4 xr[8];

#define LOAD_X(c)                                                            \
    {                                                                        \
        const float* xp = xb + (size_t)(16 * (c) + nlo) * DIN;               \
        _Pragma("unroll")                                                    \
        for (int kk = 0; kk < 4; ++kk) {                                     \
            xr[2 * kk]     = *(const float4*)(xp + kk * 32 + quad * 8);      \
            xr[2 * kk + 1] = *(const float4*)(xp + kk * 32 + quad * 8 + 4);  \
        }                                                                    \
    }

#define MAKE_XW(buf)                                                         \
    {                                                                        \
        f32x4 a0 = (f32x4)0.0f, a1 = (f32x4)0.0f;                            \
        _Pragma("unroll")                                                    \
        for (int kk = 0; kk < 4; ++kk) {                                     \
            float4 f0 = xr[2 * kk], f1 = xr[2 * kk + 1];                     \
            f16x8 a;                                                         \
            a[0]=(__fp16)f0.x; a[1]=(__fp16)f0.y; a[2]=(__fp16)f0.z;         \
            a[3]=(__fp16)f0.w; a[4]=(__fp16)f1.x; a[5]=(__fp16)f1.y;         \
            a[6]=(__fp16)f1.z; a[7]=(__fp16)f1.w;                            \
            a0 = __builtin_amdgcn_mfma_f32_16x16x32_f16(a, bfr[0][kk], a0, 0, 0, 0); \
            a1 = __builtin_amdgcn_mfma_f32_16x16x32_f16(a, bfr[1][kk], a1, 0, 0, 0); \
        }                                                                    \
        _Pragma("unroll")                                                    \
        for (int r = 0; r < 4; ++r) {                                        \
            xwb[buf][quad * 4 + r][32 * wv + nlo]      = a0[r] + bias0;      \
            xwb[buf][quad * 4 + r][32 * wv + 16 + nlo] = a1[r] + bias1;      \
        }                                                                    \
    }

    if (tid < DH) hseg[0][tid >> 4][tid & 15] = (__fp16)h0[(size_t)b * DH + tid];

    LOAD_X(0);
    MAKE_XW(0);          // compiler inserts the vmcnt wait for xr
    LOAD_X(1);
    __syncthreads();     // one full drain in prologue only

    float* orow = out + (size_t)b * TSEQ * DH + o;

#pragma unroll 1
    for (int c = 0; c < NCH; ++c) {
        if (c + 1 < NCH) {
            MAKE_XW((c + 1) & 1);                    // xw for next chunk (other buffer)
            LOAD_X(c + 2 < NCH ? c + 2 : 0);         // prefetch x two chunks ahead
        }
        const float* xwr = &xwb[c & 1][0][0];
        float* oc = orow + (size_t)(16 * c) * DH;

#pragma unroll
        for (int s = 0; s < 16; ++s) {
            const float xw_s = xwr[s * DH + o];      // issued early, used at tanh
            const int p = s & 1;                     // ping-pong parity (compile-time)
            const uint4* hp = (const uint4*)&hseg[p][sig][0];
            uint4 v0 = hp[0], v1 = hp[1];
            h2 ha = bc_h2(v0.x), hb = bc_h2(v0.y), hc = bc_h2(v0.z), hd = bc_h2(v0.w);
            h2 he = bc_h2(v1.x), hf = bc_h2(v1.y), hg = bc_h2(v1.z), hh = bc_h2(v1.w);

            float P[8];
#pragma unroll
            for (int r = 0; r < 8; ++r) {
                P[r] = __builtin_amdgcn_fdot2(w[r][0], ha, 0.0f, false);
                P[r] = __builtin_amdgcn_fdot2(w[r][1], hb, P[r], false);
                P[r] = __builtin_amdgcn_fdot2(w[r][2], hc, P[r], false);
                P[r] = __builtin_amdgcn_fdot2(w[r][3], hd, P[r], false);
                P[r] = __builtin_amdgcn_fdot2(w[r][4], he, P[r], false);
                P[r] = __builtin_amdgcn_fdot2(w[r][5], hf, P[r], false);
                P[r] = __builtin_amdgcn_fdot2(w[r][6], hg, P[r], false);
                P[r] = __builtin_amdgcn_fdot2(w[r][7], hh, P[r], false);
            }

            // butterfly over tid bits {0,1,3} (DPP) then bit5 (ds_bpermute).
            float S0 = P[0] + DPP_XOR1(P[1]);
            float S1 = P[2] + DPP_XOR1(P[3]);
            float S2 = P[4] + DPP_XOR1(P[5]);
            float S3 = P[6] + DPP_XOR1(P[7]);
            float T0 = S0 + DPP_XOR2(S1);
            float T1 = S2 + DPP_XOR2(S3);
            float U  = T0 + DPP_XOR8(T1);
            float dot = pair_sum32(U, lane);

            if (!(tid & 32)) {                       // one owner per output
                float pre = xw_s + dot;
                // tanh(x) = 1 - 2/(e^(2x)+1)
                float e  = __expf(2.0f * pre);
                float hn = 1.0f - 2.0f * __builtin_amdgcn_rcpf(e + 1.0f);
                hseg[p ^ 1][o >> 4][o & 15] = (__fp16)hn;
                oc[(size_t)s * DH] = hn;             // fire-and-forget
            }
            // barrier WITHOUT vmcnt drain: only LDS must be visible.
            asm volatile("s_waitcnt lgkmcnt(0)\n\ts_barrier" ::: "memory");
        }
    }
#undef LOAD_X
#undef MAKE_XW
}

extern "C" void kernel_launch(void* const* d_in, const int* in_sizes, int n_in,
                              void* d_out, int out_size, void* d_ws, size_t ws_size,
                              hipStream_t stream) {
    const float* x    = (const float*)d_in[0];
    const float* h0   = (const float*)d_in[1];
    const float* W    = (const float*)d_in[2];
    const float* bias = (const float*)d_in[3];
    float* out = (float*)d_out;

    rnn_fused<<<BATCH, 512, 0, stream>>>(x, W, bias, h0, out);
}